// Round 5
// baseline (641.148 us; speedup 1.0000x reference)
//
#include <hip/hip_runtime.h>
#include <cstdint>

typedef float  f32x4  __attribute__((ext_vector_type(4)));
typedef __bf16 bf16x8 __attribute__((ext_vector_type(8)));
typedef int    i32x4  __attribute__((ext_vector_type(4)));
typedef unsigned short u16;
typedef u16 u16x4 __attribute__((ext_vector_type(4)));

#define TT 512

// ---------- helpers ----------
__device__ __forceinline__ u16 f2bf(float f) {
  unsigned u = __builtin_bit_cast(unsigned, f);
  unsigned r = u + 0x7fffu + ((u >> 16) & 1u);   // RNE
  return (u16)(r >> 16);
}
__device__ __forceinline__ float bflo(unsigned d) { return __builtin_bit_cast(float, d << 16); }
__device__ __forceinline__ float bfhi(unsigned d) { return __builtin_bit_cast(float, d & 0xffff0000u); }
__device__ __forceinline__ float rcpf(float x) { return __builtin_amdgcn_rcpf(x); }
__device__ __forceinline__ float fsig(float x) { return rcpf(1.f + __expf(-x)); }
__device__ __forceinline__ float ftanh(float x) { return 1.f - 2.f * rcpf(1.f + __expf(2.f * x)); }
__device__ __forceinline__ void gload_lds16(const u16* g, u16* l) {
  __builtin_amdgcn_global_load_lds((const __attribute__((address_space(1))) void*)(g),
                                   (__attribute__((address_space(3))) void*)(l), 16, 0, 0);
}

// ---------- prep (rewritten): coalesced LDS-tiled transposes ----------
// Old prep_w read weights column-strided (256 cache lines per block, 16x
// overfetch) => ~110us. New: 64x65-padded f32 tile transposes, all global
// reads/writes 64-wide coalesced. Arithmetic op-identical (fmax set, mx*(1/127),
// w/scale, rintf, clamp, casts) => bit-identical Wxb/Whq/wscale/bsum.
// Grid 33 x 256: b<16 Wx transpose (G=b>>2, 64-col slab b&3);
//                b<32 Wh absmax+quant-transpose (G=(b-16)>>2, slab (b-16)&3);
//                b==32 bias sums.
__global__ __launch_bounds__(256) void prep_w(
    const float* __restrict__ wii, const float* __restrict__ whi,
    const float* __restrict__ wif, const float* __restrict__ whf,
    const float* __restrict__ wig, const float* __restrict__ whg,
    const float* __restrict__ wio, const float* __restrict__ who,
    const float* __restrict__ bii, const float* __restrict__ bhi,
    const float* __restrict__ bif, const float* __restrict__ bhf,
    const float* __restrict__ big_, const float* __restrict__ bhg,
    const float* __restrict__ bio, const float* __restrict__ bho,
    u16* __restrict__ Wxb, signed char* __restrict__ Whq,
    float* __restrict__ wscale, float* __restrict__ bsum) {
  __shared__ float tile[64][65];
  __shared__ float red[256];
  __shared__ float scs[64];
  int b = blockIdx.x;
  int t = threadIdx.x;
  int tlo = t & 63, thi = t >> 6;

  if (b < 16) {
    // ---- Wx transpose: Wxb[(G*256+h)*256+d] = f2bf(wx_G[d*256+h]) ----
    const float* wx[4] = {wii, wif, wig, wio};
    int G = b >> 2, h0 = (b & 3) * 64;
    const float* src = wx[G];
    for (int dt = 0; dt < 4; ++dt) {
#pragma unroll
      for (int r = 0; r < 16; ++r) {
        int dl = r * 4 + thi;
        tile[dl][tlo] = src[(dt * 64 + dl) * 256 + h0 + tlo];
      }
      __syncthreads();
#pragma unroll
      for (int r = 0; r < 16; ++r) {
        int hl = r * 4 + thi;
        Wxb[(size_t)(G * 256 + h0 + hl) * 256 + dt * 64 + tlo] = f2bf(tile[tlo][hl]);
      }
      __syncthreads();
    }
  } else if (b < 32) {
    // ---- Wh quant: per-col absmax then transposed i8 quantize ----
    const float* wh[4] = {whi, whf, whg, who};
    int idx = b - 16;
    int G = idx >> 2, h0 = (idx & 3) * 64;
    const float* src = wh[G];
    float am = 0.f;
    for (int dd = 0; dd < 64; ++dd)
      am = fmaxf(am, fabsf(src[(thi * 64 + dd) * 256 + h0 + tlo]));
    red[t] = am;
    __syncthreads();
    if (t < 64) {
      float mx = fmaxf(fmaxf(red[t], red[t + 64]), fmaxf(red[t + 128], red[t + 192]));
      float scale = (mx > 0.f) ? mx * (1.f / 127.f) : 1.f;
      scs[t] = scale;
      wscale[G * 256 + h0 + t] = scale * (1.f / 127.f);
    }
    __syncthreads();
    for (int dt = 0; dt < 4; ++dt) {
#pragma unroll
      for (int r = 0; r < 16; ++r) {
        int dl = r * 4 + thi;
        tile[dl][tlo] = src[(dt * 64 + dl) * 256 + h0 + tlo];
      }
      __syncthreads();
#pragma unroll
      for (int r = 0; r < 16; ++r) {
        int hl = r * 4 + thi;
        float w = tile[tlo][hl];
        float scale = scs[hl];
        float qf = rintf(w / scale);
        qf = fminf(127.f, fmaxf(-127.f, qf));
        Whq[(size_t)(G * 256 + h0 + hl) * 256 + dt * 64 + tlo] = (signed char)(int)qf;
      }
      __syncthreads();
    }
  } else {
    const float* bx[4] = {bii, bif, big_, bio};
    const float* bh[4] = {bhi, bhf, bhg, bho};
    for (int G = 0; G < 4; ++G) bsum[G * 256 + t] = bx[G][t] + bh[G][t];
  }
}

// ---------- fused: producer (xW GEMM, t-ordered) + consumer (recurrence) ----------
// 256 wgs x 512 thr, ~129KB LDS => 1 wg/CU, all co-resident.
// p<128: consumer = verified lstm_rec body + per-round acquire-wait (unchanged).
// p>=128: producer k=p-128, round j computes strip bm=j*128+k.
// Producer rework vs round 4 (16 serialized 800cy stage drains per strip):
//  - B staged as 32KB K-HALF panels, double-buffered (Bh[2]): stage for step
//    s+1 issued BEFORE computing step s (pure LDS->MFMA) => staging latency
//    overlaps compute; one barrier per step. Same acc/epilogue as before
//    (both K-halves of bn accumulate into acc, epilogue after odd half).
//  - B swizzle: linear gload_lds dest + pre-swizzled global source
//    (u16 idx ^= (col&7)<<3 within col) + same XOR on read (rule #21 pair).
__global__ __launch_bounds__(512, 2) void lstm_fused(
    const float* __restrict__ X, const u16* __restrict__ Bt,
    const float* __restrict__ bias, const signed char* __restrict__ Whq,
    const float* __restrict__ wscale, u16* __restrict__ xWp,
    int* __restrict__ rprog, float* __restrict__ out) {
  __shared__ u16 As[128 * 256];                      // 64 KB A strip (swizzled)
  __shared__ u16 Bh[2][128 * 128];                   // 2 x 32 KB B half-panels
  __shared__ __align__(16) signed char hb[2][576];   // consumer
  int p = blockIdx.x;
  int tid = threadIdx.x;

  if (p >= 128) {
    // ================= producer =================
    int k = p - 128;
    int l = tid & 63, w8 = tid >> 6;
    int wm = w8 >> 2, wn = w8 & 3;                   // 2 row-halves x 4 col-quads
    int c = l & 15, q = l >> 4;
    int sw = (c & 7) << 4;
    int rowbase[4];
#pragma unroll
    for (int mt = 0; mt < 4; ++mt) rowbase[mt] = (wm * 64 + mt * 16 + c) * 512;

    // stage one 32KB B half-panel: Bh[BUF][i*16B] <- Bt[col=BN*128+i/16][HALF*128 + swz]
#define STAGE_BH(BN, HALF, BUF)                                                 \
    {                                                                           \
      _Pragma("unroll")                                                         \
      for (int s2 = 0; s2 < 4; ++s2) {                                          \
        int i = s2 * 512 + tid;                                                 \
        int cl = i >> 4, wk = i & 15;                                           \
        gload_lds16(Bt + (size_t)((BN) * 128 + cl) * 256 + (HALF) * 128 +       \
                        ((wk * 8) ^ ((cl & 7) << 3)),                           \
                    &Bh[BUF][0] + i * 8);                                       \
      }                                                                         \
    }

    for (int j = 0; j < 8; ++j) {
      int bm = j * 128 + k;
      __syncthreads();                               // As/Bh free (prev strip read)
      STAGE_BH(0, 0, 0)
      // stage A strip: 128 rows x 256 k, f32 -> bf16, XOR-swizzled (hides B latency)
#pragma unroll 4
      for (int jj = 0; jj < 16; ++jj) {
        int row_l = jj * 8 + w8;                     // wave reads one row contiguously
        int d = l * 4;
        int r = bm * 128 + row_l;
        int t = r >> 8, n = r & 255;
        const float4 v = *(const float4*)(X + ((size_t)n * 512 + t) * 256 + d);
        u16x4 pk;
        pk[0] = f2bf(v.x); pk[1] = f2bf(v.y); pk[2] = f2bf(v.z); pk[3] = f2bf(v.w);
        int ba = (row_l * 512 + l * 8) ^ ((row_l & 7) << 4);
        *(u16x4*)((char*)As + ba) = pk;
      }
      __syncthreads();                               // A (lgkm) + B half 0 (vmcnt) ready

      f32x4 acc[4][2];
#pragma unroll
      for (int i = 0; i < 4; ++i)
#pragma unroll
        for (int jn = 0; jn < 2; ++jn) acc[i][jn] = (f32x4){0.f, 0.f, 0.f, 0.f};

      for (int s = 0; s < 16; ++s) {                 // s = bn*2 + Khalf
        int bn = s >> 1, half = s & 1, buf = s & 1;
        if (s < 15) {                                // issue next stage BEFORE compute
          int sn = s + 1;
          STAGE_BH(sn >> 1, sn & 1, buf ^ 1)
        }
        // compute this K-half: pure LDS->MFMA
        const u16* bp = &Bh[buf][0];
#pragma unroll
        for (int kk = 0; kk < 4; ++kk) {
          int ko = half * 4 + kk;
          bf16x8 af[4], bfr[2];
          int koff  = (ko * 64 + q * 16) ^ sw;       // A involution (full-K strip)
          int koffb = (kk * 64 + q * 16) ^ sw;       // B involution (half-K panel)
#pragma unroll
          for (int mt = 0; mt < 4; ++mt)
            af[mt] = *(const bf16x8*)((const char*)As + rowbase[mt] + koff);
#pragma unroll
          for (int nt = 0; nt < 2; ++nt)
            bfr[nt] = *(const bf16x8*)((const char*)bp + (size_t)(wn * 32 + nt * 16 + c) * 256 + koffb);
#pragma unroll
          for (int mt = 0; mt < 4; ++mt)
#pragma unroll
            for (int nt = 0; nt < 2; ++nt)
              acc[mt][nt] = __builtin_amdgcn_mfma_f32_16x16x32_bf16(af[mt], bfr[nt], acc[mt][nt], 0, 0, 0);
        }
        if (half == 1) {
          // epilogue for bn (identical packing to verified kernel)
#pragma unroll
          for (int mt = 0; mt < 4; ++mt) {
            int tm = bm * 8 + wm * 4 + mt;
#pragma unroll
            for (int nt = 0; nt < 2; ++nt) {
              int tn = bn * 8 + wn * 2 + nt;
              float bv = bias[tn * 16 + c];
              u16x4 pk;
#pragma unroll
              for (int r = 0; r < 4; ++r) pk[r] = f2bf(acc[mt][nt][r] + bv);
              *reinterpret_cast<u16x4*>(xWp + ((size_t)(tm * 64 + tn) * 256 + l * 4)) = pk;
              acc[mt][nt] = (f32x4){0.f, 0.f, 0.f, 0.f};
            }
          }
        }
        __syncthreads();             // next half staged (vmcnt0) + reads of buf done
      }
      if (tid == 0)
        __hip_atomic_fetch_add(&rprog[j], 1, __ATOMIC_RELEASE, __HIP_MEMORY_SCOPE_AGENT);
    }
#undef STAGE_BH
    return;
  }

  // ================= consumer (verified lstm_rec + round waits) =================
  int xcd = p & 7, q8 = (p >> 3) & 7, tsel = p >> 6;
  int G = xcd * 2 + tsel;        // 16-row tile id; 8 co-XCD sharers
  int wid = tid >> 6, l = tid & 63;
  int c = l & 15, q = (l >> 4) & 3;
  int tt = q >> 1, rsel = q & 1;

  for (int i = tid; i < 288; i += 512) ((int*)hb)[i] = 0;

  // Wh i8 fragments: [gate][tt-tile][kstep] -> forced into AGPRs by asm "a" use
  i32x4 bw[4][2][4];
#pragma unroll
  for (int g = 0; g < 4; ++g)
#pragma unroll
    for (int ttl = 0; ttl < 2; ++ttl) {
      int col = g * 256 + wid * 32 + ttl * 16 + c;
#pragma unroll
      for (int ks = 0; ks < 4; ++ks)
        bw[g][ttl][ks] = *reinterpret_cast<const i32x4*>(Whq + (size_t)col * 256 + ks * 64 + q * 16);
    }
  float sc8[4];
#pragma unroll
  for (int g = 0; g < 4; ++g) sc8[g] = wscale[g * 256 + wid * 32 + tt * 16 + c];

  // xW: tile tm = t*16 + G; this wg's rows are regs {2*(q8&1), +1} of quad q8>>1
  const char* xbase = (const char*)xWp + (size_t)G * 32768;
  int xoff[4];
#pragma unroll
  for (int g = 0; g < 4; ++g) {
    int tn = g * 16 + wid * 2 + tt;
    xoff[g] = tn * 512 + (((q8 >> 1) * 16 + c) * 8) + (q8 & 1) * 4;
  }

  // wait for round 0 (t=0..63) before touching xWp
  if (tid == 0) {
    while (__hip_atomic_load(&rprog[0], __ATOMIC_RELAXED, __HIP_MEMORY_SCOPE_AGENT) < 128)
      __builtin_amdgcn_s_sleep(8);
    (void)__hip_atomic_load(&rprog[0], __ATOMIC_ACQUIRE, __HIP_MEMORY_SCOPE_AGENT);
  }
  __syncthreads();

  unsigned xw0[4], xw1[4];
#pragma unroll
  for (int g = 0; g < 4; ++g) xw0[g] = *(const unsigned*)(xbase + xoff[g]);   // t=0
  xbase += 524288;   // -> t=1

  i32x4 zacc = (i32x4){0, 0, 0, 0};
  float cs = 0.f, hh = 0.f;
  __syncthreads();

#define STEP(CUR, XW_CUR, XW_NXT)                                               \
  {                                                                             \
    _Pragma("unroll")                                                           \
    for (int g = 0; g < 4; ++g) XW_NXT[g] = *(const unsigned*)(xbase + xoff[g]);\
    const signed char* hr = hb[CUR ^ 1];                                        \
    i32x4 acc[4][2];                                                            \
    {                                                                           \
      i32x4 a0 = *(const i32x4*)(hr + (c & 1) * 288 + q * 16);                  \
      _Pragma("unroll")                                                         \
      for (int g = 0; g < 4; ++g) {                                             \
        __asm__("v_mfma_i32_16x16x64_i8 %0, %1, %2, %3"                         \
                : "=&v"(acc[g][0]) : "v"(a0), "a"(bw[g][0][0]), "v"(zacc));     \
        __asm__("v_mfma_i32_16x16x64_i8 %0, %1, %2, %3"                         \
                : "=&v"(acc[g][1]) : "v"(a0), "a"(bw[g][1][0]), "v"(zacc));     \
      }                                                                         \
    }                                                                           \
    _Pragma("unroll")                                                           \
    for (int ks = 1; ks < 4; ++ks) {                                            \
      i32x4 a = *(const i32x4*)(hr + (c & 1) * 288 + ks * 64 + q * 16);         \
      _Pragma("unroll")                                                         \
      for (int g = 0; g < 4; ++g) {                                             \
        __asm__("v_mfma_i32_16x16x64_i8 %0, %1, %2, %0"                         \
                : "+v"(acc[g][0]) : "v"(a), "a"(bw[g][0][ks]));                 \
        __asm__("v_mfma_i32_16x16x64_i8 %0, %1, %2, %0"                         \
                : "+v"(acc[g][1]) : "v"(a), "a"(bw[g][1][ks]));                 \
      }                                                                         \
    }                                                                           \
    __asm__ volatile("s_nop 7\n\ts_nop 7\n\ts_nop 7");  /* MFMA->VALU hazard */ \
    float a4[4];                                                                \
    _Pragma("unroll")                                                           \
    for (int g = 0; g < 4; ++g) {                                               \
      int e = tt ? (rsel ? acc[g][1][1] : acc[g][1][0])                         \
                 : (rsel ? acc[g][0][1] : acc[g][0][0]);                        \
      unsigned d = XW_CUR[g];                                                   \
      float xv = rsel ? bfhi(d) : bflo(d);                                      \
      a4[g] = (float)e * sc8[g] + xv;                                           \
    }                                                                           \
    float gi = fsig(a4[0]);                                                     \
    float gf = fsig(a4[1]);                                                     \
    float gg = ftanh(a4[2]);                                                    \
    float go = fsig(a4[3]);                                                     \
    cs = gf * cs + gi * gg;                                                     \
    hh = go * ftanh(cs);                                                        \
    int hq = (int)rintf(hh * 127.f);                                            \
    hb[CUR][rsel * 288 + wid * 32 + tt * 16 + c] = (signed char)hq;             \
    xbase += 524288;                                                            \
    __builtin_amdgcn_s_waitcnt(0xC07F);  /* lgkmcnt(0) only, vmcnt in flight */ \
    __builtin_amdgcn_s_barrier();                                               \
  }

  for (int t = 0; t < TT; t += 2) {
    STEP(0, xw0, xw1)
    if (((t + 2) & 63) == 0 && (t + 2) < TT) {
      // next STEP prefetches t+2 (first step of round (t+2)/64): wait for it
      int j = (t + 2) >> 6;
      if (tid == 0) {
        while (__hip_atomic_load(&rprog[j], __ATOMIC_RELAXED, __HIP_MEMORY_SCOPE_AGENT) < 128)
          __builtin_amdgcn_s_sleep(8);
        (void)__hip_atomic_load(&rprog[j], __ATOMIC_ACQUIRE, __HIP_MEMORY_SCOPE_AGENT);
      }
      __syncthreads();
    }
    STEP(1, xw1, xw0)
  }
#undef STEP

  {
    int n = G * 16 + q8 * 2 + rsel;
    int hu = wid * 32 + tt * 16 + c;
    out[(size_t)n * 256 + hu] = hh;
    out[65536 + (size_t)n * 256 + hu] = cs;
  }
}

// ---------- launch ----------
extern "C" void kernel_launch(void* const* d_in, const int* in_sizes, int n_in,
                              void* d_out, int out_size, void* d_ws, size_t ws_size,
                              hipStream_t stream) {
  const float* x   = (const float*)d_in[0];
  const float* wii = (const float*)d_in[1];
  const float* whi = (const float*)d_in[2];
  const float* wif = (const float*)d_in[3];
  const float* whf = (const float*)d_in[4];
  const float* wig = (const float*)d_in[5];
  const float* whg = (const float*)d_in[6];
  const float* wio = (const float*)d_in[7];
  const float* who = (const float*)d_in[8];
  const float* bii = (const float*)d_in[9];
  const float* bhi = (const float*)d_in[10];
  const float* bif = (const float*)d_in[11];
  const float* bhf = (const float*)d_in[12];
  const float* big_ = (const float*)d_in[13];
  const float* bhg = (const float*)d_in[14];
  const float* bio = (const float*)d_in[15];
  const float* bho = (const float*)d_in[16];

  char* ws = (char*)d_ws;
  int*   rprog  = (int*)(ws);                         // 64 B (zeroed per launch)
  u16*   Wxb    = (u16*)(ws + 67108864);              //    524,288 B
  signed char* Whq = (signed char*)(ws + 67633152);   //    262,144 B
  float* wscale = (float*)(ws + 67895296);            //      4,096 B
  float* bsum   = (float*)(ws + 67899392);            //      4,096 B
  u16*   xWp    = (u16*)(ws + 67903488);              // 268,435,456 B + 576 KB prefetch pad
  float* out = (float*)d_out;

  hipMemsetAsync(rprog, 0, 64, stream);
  prep_w<<<33, 256, 0, stream>>>(wii, whi, wif, whf, wig, whg, wio, who,
                                 bii, bhi, bif, bhf, big_, bhg, bio, bho,
                                 Wxb, Whq, wscale, bsum);
  lstm_fused<<<256, 512, 0, stream>>>(x, Wxb, bsum, Whq, wscale, xWp, rprog, out);
}

// Round 7
// 630.778 us; speedup vs baseline: 1.0164x; 1.0164x over previous
//
#include <hip/hip_runtime.h>
#include <cstdint>

typedef float  f32x4  __attribute__((ext_vector_type(4)));
typedef __bf16 bf16x8 __attribute__((ext_vector_type(8)));
typedef int    i32x4  __attribute__((ext_vector_type(4)));
typedef unsigned short u16;
typedef u16 u16x4 __attribute__((ext_vector_type(4)));

#define TT 512

// ---------- helpers ----------
__device__ __forceinline__ u16 f2bf(float f) {
  unsigned u = __builtin_bit_cast(unsigned, f);
  unsigned r = u + 0x7fffu + ((u >> 16) & 1u);   // RNE
  return (u16)(r >> 16);
}
__device__ __forceinline__ float bflo(unsigned d) { return __builtin_bit_cast(float, d << 16); }
__device__ __forceinline__ float bfhi(unsigned d) { return __builtin_bit_cast(float, d & 0xffff0000u); }
__device__ __forceinline__ float rcpf(float x) { return __builtin_amdgcn_rcpf(x); }
__device__ __forceinline__ float fsig(float x) { return rcpf(1.f + __expf(-x)); }
__device__ __forceinline__ float ftanh(float x) { return 1.f - 2.f * rcpf(1.f + __expf(2.f * x)); }
__device__ __forceinline__ void gload_lds16(const u16* g, u16* l) {
  __builtin_amdgcn_global_load_lds((const __attribute__((address_space(1))) void*)(g),
                                   (__attribute__((address_space(3))) void*)(l), 16, 0, 0);
}

// ---------- single fused kernel (resubmit of round 6: infra failure, no
// counters; structural audit found no deadlock -- see journal) ----------
// 256 wgs x 512 thr, ~129KB LDS => 1 wg/CU, all 256 co-resident (HW-enforced).
// p>=128: producer k=p-128.
//   PREP (replaces separate prep_w kernel, whose launch/gap cost ~120us wall):
//     wg k owns cols k*8..k*8+7 of BOTH Wx (transpose->bf16) and Wh (wave-
//     shuffle absmax -> i8 quant). Arithmetic op-identical to verified prep_w
//     => bit-identical Wxb/Whq/wscale/bsum. wg0 (k=0) also does bias sums.
//     Then: syncthreads + tid0 RELEASE/AGENT inc of prep_cnt (rprog[8]);
//     spin until ==128 + ACQUIRE before reading Wxb/bsum.
//   STRIPS: identical to round-5 (double-buffered 32KB B half-panels,
//     stage-before-compute, one barrier/half; rprog[j] release per round).
// p<128: consumer = verified lstm_rec body + prep-wait before Whq/wscale loads
//   + per-round acquire-waits (unchanged otherwise).
__global__ __launch_bounds__(512, 2) void lstm_fused(
    const float* __restrict__ X,
    const float* __restrict__ wii, const float* __restrict__ whi,
    const float* __restrict__ wif, const float* __restrict__ whf,
    const float* __restrict__ wig, const float* __restrict__ whg,
    const float* __restrict__ wio, const float* __restrict__ who,
    const float* __restrict__ bii, const float* __restrict__ bhi,
    const float* __restrict__ bif, const float* __restrict__ bhf,
    const float* __restrict__ big_, const float* __restrict__ bhg,
    const float* __restrict__ bio, const float* __restrict__ bho,
    u16* __restrict__ Wxb, signed char* __restrict__ Whq,
    float* __restrict__ wscale, float* __restrict__ bsum,
    u16* __restrict__ xWp, int* __restrict__ rprog, float* __restrict__ out) {
  __shared__ u16 As[128 * 256];                      // 64 KB A strip (swizzled)
  __shared__ u16 Bh[2][128 * 128];                   // 2 x 32 KB B half-panels
  __shared__ __align__(16) signed char hb[2][576];   // consumer
  int p = blockIdx.x;
  int tid = threadIdx.x;

  if (p >= 128) {
    // ================= producer =================
    int k = p - 128;

    // ---- in-kernel prep: cols k*8..k*8+7 of Wx and Wh ----
    {
      int cl = tid >> 6, dl = tid & 63;   // col-local (wave id), d-lane
      int C = k * 8 + cl;                 // 0..1023
      int G = C >> 8, h = C & 255;
      const float* wxp[4] = {wii, wif, wig, wio};
      const float* whp[4] = {whi, whf, whg, who};
      const float* sx = wxp[G];
#pragma unroll
      for (int i = 0; i < 4; ++i) {
        int d = i * 64 + dl;
        Wxb[(size_t)C * 256 + d] = f2bf(sx[(size_t)d * 256 + h]);
      }
      const float* sh = whp[G];
      float wv[4];
      float am = 0.f;
#pragma unroll
      for (int i = 0; i < 4; ++i) {
        int d = i * 64 + dl;
        wv[i] = sh[(size_t)d * 256 + h];
        am = fmaxf(am, fabsf(wv[i]));
      }
#pragma unroll
      for (int off = 32; off > 0; off >>= 1)
        am = fmaxf(am, __shfl_xor(am, off, 64));
      float scale = (am > 0.f) ? am * (1.f / 127.f) : 1.f;
      if (dl == 0) wscale[C] = scale * (1.f / 127.f);   // combined w*h scale
#pragma unroll
      for (int i = 0; i < 4; ++i) {
        float qf = rintf(wv[i] / scale);
        qf = fminf(127.f, fmaxf(-127.f, qf));
        Whq[(size_t)C * 256 + i * 64 + dl] = (signed char)(int)qf;
      }
      if (k == 0 && tid < 256) {
        const float* bx[4] = {bii, bif, big_, bio};
        const float* bh4[4] = {bhi, bhf, bhg, bho};
        for (int Gg = 0; Gg < 4; ++Gg) bsum[Gg * 256 + tid] = bx[Gg][tid] + bh4[Gg][tid];
      }
      __syncthreads();                    // drain all waves' stores (vmcnt0)
      if (tid == 0)
        __hip_atomic_fetch_add(&rprog[8], 1, __ATOMIC_RELEASE, __HIP_MEMORY_SCOPE_AGENT);
      if (tid == 0) {
        while (__hip_atomic_load(&rprog[8], __ATOMIC_RELAXED, __HIP_MEMORY_SCOPE_AGENT) < 128)
          __builtin_amdgcn_s_sleep(8);
        (void)__hip_atomic_load(&rprog[8], __ATOMIC_ACQUIRE, __HIP_MEMORY_SCOPE_AGENT);
      }
      __syncthreads();                    // all prep visible; Wxb/bsum readable
    }

    const u16* Bt = Wxb;
    int l = tid & 63, w8 = tid >> 6;
    int wm = w8 >> 2, wn = w8 & 3;                   // 2 row-halves x 4 col-quads
    int c = l & 15, q = l >> 4;
    int sw = (c & 7) << 4;
    int rowbase[4];
#pragma unroll
    for (int mt = 0; mt < 4; ++mt) rowbase[mt] = (wm * 64 + mt * 16 + c) * 512;

    // stage one 32KB B half-panel: Bh[BUF][i*16B] <- Bt[col=BN*128+i/16][HALF*128 + swz]
#define STAGE_BH(BN, HALF, BUF)                                                 \
    {                                                                           \
      _Pragma("unroll")                                                         \
      for (int s2 = 0; s2 < 4; ++s2) {                                          \
        int i = s2 * 512 + tid;                                                 \
        int cl2 = i >> 4, wk = i & 15;                                          \
        gload_lds16(Bt + (size_t)((BN) * 128 + cl2) * 256 + (HALF) * 128 +      \
                        ((wk * 8) ^ ((cl2 & 7) << 3)),                          \
                    &Bh[BUF][0] + i * 8);                                       \
      }                                                                         \
    }

    for (int j = 0; j < 8; ++j) {
      int bm = j * 128 + k;
      __syncthreads();                               // As/Bh free (prev strip read)
      STAGE_BH(0, 0, 0)
      // stage A strip: 128 rows x 256 k, f32 -> bf16, XOR-swizzled (hides B latency)
#pragma unroll 4
      for (int jj = 0; jj < 16; ++jj) {
        int row_l = jj * 8 + w8;                     // wave reads one row contiguously
        int d = l * 4;
        int r = bm * 128 + row_l;
        int t = r >> 8, n = r & 255;
        const float4 v = *(const float4*)(X + ((size_t)n * 512 + t) * 256 + d);
        u16x4 pk;
        pk[0] = f2bf(v.x); pk[1] = f2bf(v.y); pk[2] = f2bf(v.z); pk[3] = f2bf(v.w);
        int ba = (row_l * 512 + l * 8) ^ ((row_l & 7) << 4);
        *(u16x4*)((char*)As + ba) = pk;
      }
      __syncthreads();                               // A (lgkm) + B half 0 (vmcnt) ready

      f32x4 acc[4][2];
#pragma unroll
      for (int i = 0; i < 4; ++i)
#pragma unroll
        for (int jn = 0; jn < 2; ++jn) acc[i][jn] = (f32x4){0.f, 0.f, 0.f, 0.f};

      for (int s = 0; s < 16; ++s) {                 // s = bn*2 + Khalf
        int bn = s >> 1, half = s & 1, buf = s & 1;
        if (s < 15) {                                // issue next stage BEFORE compute
          int sn = s + 1;
          STAGE_BH(sn >> 1, sn & 1, buf ^ 1)
        }
        // compute this K-half: pure LDS->MFMA
        const u16* bp = &Bh[buf][0];
#pragma unroll
        for (int kk = 0; kk < 4; ++kk) {
          int ko = half * 4 + kk;
          bf16x8 af[4], bfr[2];
          int koff  = (ko * 64 + q * 16) ^ sw;       // A involution (full-K strip)
          int koffb = (kk * 64 + q * 16) ^ sw;       // B involution (half-K panel)
#pragma unroll
          for (int mt = 0; mt < 4; ++mt)
            af[mt] = *(const bf16x8*)((const char*)As + rowbase[mt] + koff);
#pragma unroll
          for (int nt = 0; nt < 2; ++nt)
            bfr[nt] = *(const bf16x8*)((const char*)bp + (size_t)(wn * 32 + nt * 16 + c) * 256 + koffb);
#pragma unroll
          for (int mt = 0; mt < 4; ++mt)
#pragma unroll
            for (int nt = 0; nt < 2; ++nt)
              acc[mt][nt] = __builtin_amdgcn_mfma_f32_16x16x32_bf16(af[mt], bfr[nt], acc[mt][nt], 0, 0, 0);
        }
        if (half == 1) {
          // epilogue for bn (identical packing to verified kernel)
#pragma unroll
          for (int mt = 0; mt < 4; ++mt) {
            int tm = bm * 8 + wm * 4 + mt;
#pragma unroll
            for (int nt = 0; nt < 2; ++nt) {
              int tn = bn * 8 + wn * 2 + nt;
              float bv = bsum[tn * 16 + c];
              u16x4 pk;
#pragma unroll
              for (int r = 0; r < 4; ++r) pk[r] = f2bf(acc[mt][nt][r] + bv);
              *reinterpret_cast<u16x4*>(xWp + ((size_t)(tm * 64 + tn) * 256 + l * 4)) = pk;
              acc[mt][nt] = (f32x4){0.f, 0.f, 0.f, 0.f};
            }
          }
        }
        __syncthreads();             // next half staged (vmcnt0) + reads of buf done
      }
      if (tid == 0)
        __hip_atomic_fetch_add(&rprog[j], 1, __ATOMIC_RELEASE, __HIP_MEMORY_SCOPE_AGENT);
    }
#undef STAGE_BH
    return;
  }

  // ================= consumer (verified lstm_rec + waits) =================
  int xcd = p & 7, q8 = (p >> 3) & 7, tsel = p >> 6;
  int G = xcd * 2 + tsel;        // 16-row tile id; 8 co-XCD sharers
  int wid = tid >> 6, l = tid & 63;
  int c = l & 15, q = (l >> 4) & 3;
  int tt = q >> 1, rsel = q & 1;

  for (int i = tid; i < 288; i += 512) ((int*)hb)[i] = 0;

  // wait for in-kernel prep (Whq/wscale valid) before fragment loads
  if (tid == 0) {
    while (__hip_atomic_load(&rprog[8], __ATOMIC_RELAXED, __HIP_MEMORY_SCOPE_AGENT) < 128)
      __builtin_amdgcn_s_sleep(8);
    (void)__hip_atomic_load(&rprog[8], __ATOMIC_ACQUIRE, __HIP_MEMORY_SCOPE_AGENT);
  }
  __syncthreads();

  // Wh i8 fragments: [gate][tt-tile][kstep] -> forced into AGPRs by asm "a" use
  i32x4 bw[4][2][4];
#pragma unroll
  for (int g = 0; g < 4; ++g)
#pragma unroll
    for (int ttl = 0; ttl < 2; ++ttl) {
      int col = g * 256 + wid * 32 + ttl * 16 + c;
#pragma unroll
      for (int ks = 0; ks < 4; ++ks)
        bw[g][ttl][ks] = *reinterpret_cast<const i32x4*>(Whq + (size_t)col * 256 + ks * 64 + q * 16);
    }
  float sc8[4];
#pragma unroll
  for (int g = 0; g < 4; ++g) sc8[g] = wscale[g * 256 + wid * 32 + tt * 16 + c];

  // xW: tile tm = t*16 + G; this wg's rows are regs {2*(q8&1), +1} of quad q8>>1
  const char* xbase = (const char*)xWp + (size_t)G * 32768;
  int xoff[4];
#pragma unroll
  for (int g = 0; g < 4; ++g) {
    int tn = g * 16 + wid * 2 + tt;
    xoff[g] = tn * 512 + (((q8 >> 1) * 16 + c) * 8) + (q8 & 1) * 4;
  }

  // wait for round 0 (t=0..63) before touching xWp
  if (tid == 0) {
    while (__hip_atomic_load(&rprog[0], __ATOMIC_RELAXED, __HIP_MEMORY_SCOPE_AGENT) < 128)
      __builtin_amdgcn_s_sleep(8);
    (void)__hip_atomic_load(&rprog[0], __ATOMIC_ACQUIRE, __HIP_MEMORY_SCOPE_AGENT);
  }
  __syncthreads();

  unsigned xw0[4], xw1[4];
#pragma unroll
  for (int g = 0; g < 4; ++g) xw0[g] = *(const unsigned*)(xbase + xoff[g]);   // t=0
  xbase += 524288;   // -> t=1

  i32x4 zacc = (i32x4){0, 0, 0, 0};
  float cs = 0.f, hh = 0.f;
  __syncthreads();

#define STEP(CUR, XW_CUR, XW_NXT)                                               \
  {                                                                             \
    _Pragma("unroll")                                                           \
    for (int g = 0; g < 4; ++g) XW_NXT[g] = *(const unsigned*)(xbase + xoff[g]);\
    const signed char* hr = hb[CUR ^ 1];                                        \
    i32x4 acc[4][2];                                                            \
    {                                                                           \
      i32x4 a0 = *(const i32x4*)(hr + (c & 1) * 288 + q * 16);                  \
      _Pragma("unroll")                                                         \
      for (int g = 0; g < 4; ++g) {                                             \
        __asm__("v_mfma_i32_16x16x64_i8 %0, %1, %2, %3"                         \
                : "=&v"(acc[g][0]) : "v"(a0), "a"(bw[g][0][0]), "v"(zacc));     \
        __asm__("v_mfma_i32_16x16x64_i8 %0, %1, %2, %3"                         \
                : "=&v"(acc[g][1]) : "v"(a0), "a"(bw[g][1][0]), "v"(zacc));     \
      }                                                                         \
    }                                                                           \
    _Pragma("unroll")                                                           \
    for (int ks = 1; ks < 4; ++ks) {                                            \
      i32x4 a = *(const i32x4*)(hr + (c & 1) * 288 + ks * 64 + q * 16);         \
      _Pragma("unroll")                                                         \
      for (int g = 0; g < 4; ++g) {                                             \
        __asm__("v_mfma_i32_16x16x64_i8 %0, %1, %2, %0"                         \
                : "+v"(acc[g][0]) : "v"(a), "a"(bw[g][0][ks]));                 \
        __asm__("v_mfma_i32_16x16x64_i8 %0, %1, %2, %0"                         \
                : "+v"(acc[g][1]) : "v"(a), "a"(bw[g][1][ks]));                 \
      }                                                                         \
    }                                                                           \
    __asm__ volatile("s_nop 7\n\ts_nop 7\n\ts_nop 7");  /* MFMA->VALU hazard */ \
    float a4[4];                                                                \
    _Pragma("unroll")                                                           \
    for (int g = 0; g < 4; ++g) {                                               \
      int e = tt ? (rsel ? acc[g][1][1] : acc[g][1][0])                         \
                 : (rsel ? acc[g][0][1] : acc[g][0][0]);                        \
      unsigned d = XW_CUR[g];                                                   \
      float xv = rsel ? bfhi(d) : bflo(d);                                      \
      a4[g] = (float)e * sc8[g] + xv;                                           \
    }                                                                           \
    float gi = fsig(a4[0]);                                                     \
    float gf = fsig(a4[1]);                                                     \
    float gg = ftanh(a4[2]);                                                    \
    float go = fsig(a4[3]);                                                     \
    cs = gf * cs + gi * gg;                                                     \
    hh = go * ftanh(cs);                                                        \
    int hq = (int)rintf(hh * 127.f);                                            \
    hb[CUR][rsel * 288 + wid * 32 + tt * 16 + c] = (signed char)hq;             \
    xbase += 524288;                                                            \
    __builtin_amdgcn_s_waitcnt(0xC07F);  /* lgkmcnt(0) only, vmcnt in flight */ \
    __builtin_amdgcn_s_barrier();                                               \
  }

  for (int t = 0; t < TT; t += 2) {
    STEP(0, xw0, xw1)
    if (((t + 2) & 63) == 0 && (t + 2) < TT) {
      // next STEP prefetches t+2 (first step of round (t+2)/64): wait for it
      int j = (t + 2) >> 6;
      if (tid == 0) {
        while (__hip_atomic_load(&rprog[j], __ATOMIC_RELAXED, __HIP_MEMORY_SCOPE_AGENT) < 128)
          __builtin_amdgcn_s_sleep(8);
        (void)__hip_atomic_load(&rprog[j], __ATOMIC_ACQUIRE, __HIP_MEMORY_SCOPE_AGENT);
      }
      __syncthreads();
    }
    STEP(1, xw1, xw0)
  }
#undef STEP

  {
    int n = G * 16 + q8 * 2 + rsel;
    int hu = wid * 32 + tt * 16 + c;
    out[(size_t)n * 256 + hu] = hh;
    out[65536 + (size_t)n * 256 + hu] = cs;
  }
}

// ---------- launch ----------
extern "C" void kernel_launch(void* const* d_in, const int* in_sizes, int n_in,
                              void* d_out, int out_size, void* d_ws, size_t ws_size,
                              hipStream_t stream) {
  const float* x   = (const float*)d_in[0];
  const float* wii = (const float*)d_in[1];
  const float* whi = (const float*)d_in[2];
  const float* wif = (const float*)d_in[3];
  const float* whf = (const float*)d_in[4];
  const float* wig = (const float*)d_in[5];
  const float* whg = (const float*)d_in[6];
  const float* wio = (const float*)d_in[7];
  const float* who = (const float*)d_in[8];
  const float* bii = (const float*)d_in[9];
  const float* bhi = (const float*)d_in[10];
  const float* bif = (const float*)d_in[11];
  const float* bhf = (const float*)d_in[12];
  const float* big_ = (const float*)d_in[13];
  const float* bhg = (const float*)d_in[14];
  const float* bio = (const float*)d_in[15];
  const float* bho = (const float*)d_in[16];

  char* ws = (char*)d_ws;
  int*   rprog  = (int*)(ws);                         // rprog[0..7] + prep_cnt at [8]
  u16*   Wxb    = (u16*)(ws + 67108864);              //    524,288 B
  signed char* Whq = (signed char*)(ws + 67633152);   //    262,144 B
  float* wscale = (float*)(ws + 67895296);            //      4,096 B
  float* bsum   = (float*)(ws + 67899392);            //      4,096 B
  u16*   xWp    = (u16*)(ws + 67903488);              // 268,435,456 B + 576 KB prefetch pad
  float* out = (float*)d_out;

  hipMemsetAsync(rprog, 0, 64, stream);
  lstm_fused<<<256, 512, 0, stream>>>(x,
                                      wii, whi, wif, whf, wig, whg, wio, who,
                                      bii, bhi, bif, bhf, big_, bhg, bio, bho,
                                      Wxb, Whq, wscale, bsum, xWp, rprog, out);
}

// Round 9
// 627.324 us; speedup vs baseline: 1.0220x; 1.0055x over previous
//
#include <hip/hip_runtime.h>
#include <cstdint>

typedef float  f32x4  __attribute__((ext_vector_type(4)));
typedef __bf16 bf16x8 __attribute__((ext_vector_type(8)));
typedef int    i32x4  __attribute__((ext_vector_type(4)));
typedef unsigned short u16;
typedef u16 u16x4 __attribute__((ext_vector_type(4)));

#define TT 512

// ---------- helpers ----------
__device__ __forceinline__ u16 f2bf(float f) {
  unsigned u = __builtin_bit_cast(unsigned, f);
  unsigned r = u + 0x7fffu + ((u >> 16) & 1u);   // RNE
  return (u16)(r >> 16);
}
__device__ __forceinline__ float bflo(unsigned d) { return __builtin_bit_cast(float, d << 16); }
__device__ __forceinline__ float bfhi(unsigned d) { return __builtin_bit_cast(float, d & 0xffff0000u); }
__device__ __forceinline__ float rcpf(float x) { return __builtin_amdgcn_rcpf(x); }
__device__ __forceinline__ float fsig(float x) { return rcpf(1.f + __expf(-x)); }
__device__ __forceinline__ float ftanh(float x) { return 1.f - 2.f * rcpf(1.f + __expf(2.f * x)); }
__device__ __forceinline__ void gload_lds16(const u16* g, u16* l) {
  __builtin_amdgcn_global_load_lds((const __attribute__((address_space(1))) void*)(g),
                                   (__attribute__((address_space(3))) void*)(l), 16, 0, 0);
}

// ---------- single fused kernel (r7 base + producer LDS reshaped to the
// m201-proven conflict-free geometry) ----------
// SQ_LDS_BANK_CONFLICT = 12.58M, BIT-IDENTICAL r3->r7 across a full B-staging
// rewrite => source is the A-path ds ops (consumer measured 0 standalone).
// 12.58M/128 producer CUs = 41us/CU on the MFMA operand path = the bulk of
// the T_strip model gap (~50us measured vs ~15 modeled).
// Fix: As and Bh become K-chunk-major tiles [128 rows][64 bf16] (128B row
// stride) with st_16x32 swizzle: byte ^= ((byte>>9)&1)<<5 (bit9 = row&4).
//   A(row,k):  byte = (k>>6)*16384 + row*128 + (k&63)*2, ^32 iff row&4
//   B(col,kl): byte = (kl>>6)*16384 + col*128 + (kl&63)*2, ^32 iff col&4
// Writes fold the involution into the SOURCE (rule #21 pair): A's direct
// store computes the swizzled byte; B's global_load_lds keeps a linear LDS
// dst and pre-swizzles the global source. MFMA order/acc/epilogue unchanged
// => xWp bit-identical => absmax canary 0.01171875. Consumer/prep = r7.
__global__ __launch_bounds__(512, 2) void lstm_fused(
    const float* __restrict__ X,
    const float* __restrict__ wii, const float* __restrict__ whi,
    const float* __restrict__ wif, const float* __restrict__ whf,
    const float* __restrict__ wig, const float* __restrict__ whg,
    const float* __restrict__ wio, const float* __restrict__ who,
    const float* __restrict__ bii, const float* __restrict__ bhi,
    const float* __restrict__ bif, const float* __restrict__ bhf,
    const float* __restrict__ big_, const float* __restrict__ bhg,
    const float* __restrict__ bio, const float* __restrict__ bho,
    u16* __restrict__ Wxb, signed char* __restrict__ Whq,
    float* __restrict__ wscale, float* __restrict__ bsum,
    u16* __restrict__ xWp, int* __restrict__ rprog, float* __restrict__ out) {
  __shared__ u16 As[128 * 256];                      // 64 KB: 4 tiles [128][64]
  __shared__ u16 Bh[2][128 * 128];                   // 2 x 32 KB: 2 tiles [128][64]
  __shared__ __align__(16) signed char hb[2][576];   // consumer
  int p = blockIdx.x;
  int tid = threadIdx.x;

  if (p >= 128) {
    // ================= producer =================
    int k = p - 128;

    // ---- in-kernel prep: cols k*8..k*8+7 of Wx and Wh (unchanged r7) ----
    {
      int cl = tid >> 6, dl = tid & 63;   // col-local (wave id), d-lane
      int C = k * 8 + cl;                 // 0..1023
      int G = C >> 8, h = C & 255;
      const float* wxp[4] = {wii, wif, wig, wio};
      const float* whp[4] = {whi, whf, whg, who};
      const float* sx = wxp[G];
#pragma unroll
      for (int i = 0; i < 4; ++i) {
        int d = i * 64 + dl;
        Wxb[(size_t)C * 256 + d] = f2bf(sx[(size_t)d * 256 + h]);
      }
      const float* sh = whp[G];
      float wv[4];
      float am = 0.f;
#pragma unroll
      for (int i = 0; i < 4; ++i) {
        int d = i * 64 + dl;
        wv[i] = sh[(size_t)d * 256 + h];
        am = fmaxf(am, fabsf(wv[i]));
      }
#pragma unroll
      for (int off = 32; off > 0; off >>= 1)
        am = fmaxf(am, __shfl_xor(am, off, 64));
      float scale = (am > 0.f) ? am * (1.f / 127.f) : 1.f;
      if (dl == 0) wscale[C] = scale * (1.f / 127.f);   // combined w*h scale
#pragma unroll
      for (int i = 0; i < 4; ++i) {
        float qf = rintf(wv[i] / scale);
        qf = fminf(127.f, fmaxf(-127.f, qf));
        Whq[(size_t)C * 256 + i * 64 + dl] = (signed char)(int)qf;
      }
      if (k == 0 && tid < 256) {
        const float* bx[4] = {bii, bif, big_, bio};
        const float* bh4[4] = {bhi, bhf, bhg, bho};
        for (int Gg = 0; Gg < 4; ++Gg) bsum[Gg * 256 + tid] = bx[Gg][tid] + bh4[Gg][tid];
      }
      __syncthreads();                    // drain all waves' stores (vmcnt0)
      if (tid == 0)
        __hip_atomic_fetch_add(&rprog[8], 1, __ATOMIC_RELEASE, __HIP_MEMORY_SCOPE_AGENT);
      if (tid == 0) {
        while (__hip_atomic_load(&rprog[8], __ATOMIC_RELAXED, __HIP_MEMORY_SCOPE_AGENT) < 128)
          __builtin_amdgcn_s_sleep(8);
        (void)__hip_atomic_load(&rprog[8], __ATOMIC_ACQUIRE, __HIP_MEMORY_SCOPE_AGENT);
      }
      __syncthreads();                    // all prep visible; Wxb/bsum readable
    }

    const u16* Bt = Wxb;
    int l = tid & 63, w8 = tid >> 6;
    int wm = w8 >> 2, wn = w8 & 3;
    int c = l & 15, q = l >> 4;
    int swz = (c & 4) << 3;               // st_16x32 key: ^32 iff row/col bit2
    int rowb[4];
#pragma unroll
    for (int mt = 0; mt < 4; ++mt) rowb[mt] = (wm * 64 + mt * 16 + c) * 128;

    // stage 32KB B half-panel, new tiled layout via pre-swizzled source:
    // LDS 16B-unit i: kt=i>>10, coln=(i&1023)>>3, sub=i&7
    // src u16 = Wxb[BN*128+coln][HALF*128 + kt*64 + (sub*8 ^ ((coln&4)?16:0))]
#define STAGE_BH(BN, HALF, BUF)                                                 \
    {                                                                           \
      _Pragma("unroll")                                                         \
      for (int s2 = 0; s2 < 4; ++s2) {                                          \
        int i = s2 * 512 + tid;                                                 \
        int kt2 = i >> 10, coln = (i & 1023) >> 3, sub = i & 7;                 \
        gload_lds16(Bt + (size_t)((BN) * 128 + coln) * 256 + (HALF) * 128 +     \
                        kt2 * 64 + ((sub * 8) ^ ((coln & 4) ? 16 : 0)),         \
                    &Bh[BUF][0] + i * 8);                                       \
      }                                                                         \
    }

    for (int j = 0; j < 8; ++j) {
      int bm = j * 128 + k;
      __syncthreads();                               // As/Bh free (prev strip read)
      STAGE_BH(0, 0, 0)
      // stage A strip: lane loads float4 at k=l*4 of row row_l; writes 8B to
      // tile (l>>4), row row_l*128, in-row byte (l&15)*8, st_16x32 XOR
#pragma unroll 4
      for (int jj = 0; jj < 16; ++jj) {
        int row_l = jj * 8 + w8;                     // wave reads one row contiguously
        int d = l * 4;
        int r = bm * 128 + row_l;
        int t = r >> 8, n = r & 255;
        const float4 v = *(const float4*)(X + ((size_t)n * 512 + t) * 256 + d);
        u16x4 pk;
        pk[0] = f2bf(v.x); pk[1] = f2bf(v.y); pk[2] = f2bf(v.z); pk[3] = f2bf(v.w);
        int ba = ((l >> 4) * 16384 + row_l * 128 + (l & 15) * 8) ^ ((row_l & 4) ? 32 : 0);
        *(u16x4*)((char*)As + ba) = pk;
      }
      __syncthreads();                               // A (lgkm) + B half 0 (vmcnt) ready

      f32x4 acc[4][2];
#pragma unroll
      for (int i = 0; i < 4; ++i)
#pragma unroll
        for (int jn = 0; jn < 2; ++jn) acc[i][jn] = (f32x4){0.f, 0.f, 0.f, 0.f};

      for (int s = 0; s < 16; ++s) {                 // s = bn*2 + Khalf
        int bn = s >> 1, half = s & 1, buf = s & 1;
        if (s < 15) {                                // issue next stage BEFORE compute
          int sn = s + 1;
          STAGE_BH(sn >> 1, sn & 1, buf ^ 1)
        }
        const u16* bp = &Bh[buf][0];
#pragma unroll
        for (int kk = 0; kk < 4; ++kk) {
          int ko = half * 4 + kk;
          bf16x8 af[4], bfr[2];
          // A: k-chunk ko (32 elems): tile ko>>1, in-row (ko&1)*64 + q*16
          int koffA = (ko >> 1) * 16384 + ((((ko & 1) * 64) + q * 16) ^ swz);
          // B: k-local chunk kk within half: tile kk>>1, in-row (kk&1)*64+q*16
          int koffB = (kk >> 1) * 16384 + ((((kk & 1) * 64) + q * 16) ^ swz);
#pragma unroll
          for (int mt = 0; mt < 4; ++mt)
            af[mt] = *(const bf16x8*)((const char*)As + rowb[mt] + koffA);
#pragma unroll
          for (int nt = 0; nt < 2; ++nt)
            bfr[nt] = *(const bf16x8*)((const char*)bp + (wn * 32 + nt * 16 + c) * 128 + koffB);
#pragma unroll
          for (int mt = 0; mt < 4; ++mt)
#pragma unroll
            for (int nt = 0; nt < 2; ++nt)
              acc[mt][nt] = __builtin_amdgcn_mfma_f32_16x16x32_bf16(af[mt], bfr[nt], acc[mt][nt], 0, 0, 0);
        }
        if (half == 1) {
          // epilogue for bn (identical packing to verified kernel)
#pragma unroll
          for (int mt = 0; mt < 4; ++mt) {
            int tm = bm * 8 + wm * 4 + mt;
#pragma unroll
            for (int nt = 0; nt < 2; ++nt) {
              int tn = bn * 8 + wn * 2 + nt;
              float bv = bsum[tn * 16 + c];
              u16x4 pk;
#pragma unroll
              for (int r = 0; r < 4; ++r) pk[r] = f2bf(acc[mt][nt][r] + bv);
              *reinterpret_cast<u16x4*>(xWp + ((size_t)(tm * 64 + tn) * 256 + l * 4)) = pk;
              acc[mt][nt] = (f32x4){0.f, 0.f, 0.f, 0.f};
            }
          }
        }
        __syncthreads();             // next half staged (vmcnt0) + reads of buf done
      }
      if (tid == 0)
        __hip_atomic_fetch_add(&rprog[j], 1, __ATOMIC_RELEASE, __HIP_MEMORY_SCOPE_AGENT);
    }
#undef STAGE_BH
    return;
  }

  // ================= consumer (verified lstm_rec + waits; r7 byte-identical) =================
  int xcd = p & 7, q8 = (p >> 3) & 7, tsel = p >> 6;
  int G = xcd * 2 + tsel;        // 16-row tile id; 8 co-XCD sharers
  int wid = tid >> 6, l = tid & 63;
  int c = l & 15, q = (l >> 4) & 3;
  int tt = q >> 1, rsel = q & 1;

  for (int i = tid; i < 288; i += 512) ((int*)hb)[i] = 0;

  // wait for in-kernel prep (Whq/wscale valid) before fragment loads
  if (tid == 0) {
    while (__hip_atomic_load(&rprog[8], __ATOMIC_RELAXED, __HIP_MEMORY_SCOPE_AGENT) < 128)
      __builtin_amdgcn_s_sleep(8);
    (void)__hip_atomic_load(&rprog[8], __ATOMIC_ACQUIRE, __HIP_MEMORY_SCOPE_AGENT);
  }
  __syncthreads();

  // Wh i8 fragments: [gate][tt-tile][kstep] -> forced into AGPRs by asm "a" use
  i32x4 bw[4][2][4];
#pragma unroll
  for (int g = 0; g < 4; ++g)
#pragma unroll
    for (int ttl = 0; ttl < 2; ++ttl) {
      int col = g * 256 + wid * 32 + ttl * 16 + c;
#pragma unroll
      for (int ks = 0; ks < 4; ++ks)
        bw[g][ttl][ks] = *reinterpret_cast<const i32x4*>(Whq + (size_t)col * 256 + ks * 64 + q * 16);
    }
  float sc8[4];
#pragma unroll
  for (int g = 0; g < 4; ++g) sc8[g] = wscale[g * 256 + wid * 32 + tt * 16 + c];

  // xW: tile tm = t*16 + G; this wg's rows are regs {2*(q8&1), +1} of quad q8>>1
  const char* xbase = (const char*)xWp + (size_t)G * 32768;
  int xoff[4];
#pragma unroll
  for (int g = 0; g < 4; ++g) {
    int tn = g * 16 + wid * 2 + tt;
    xoff[g] = tn * 512 + (((q8 >> 1) * 16 + c) * 8) + (q8 & 1) * 4;
  }

  // wait for round 0 (t=0..63) before touching xWp
  if (tid == 0) {
    while (__hip_atomic_load(&rprog[0], __ATOMIC_RELAXED, __HIP_MEMORY_SCOPE_AGENT) < 128)
      __builtin_amdgcn_s_sleep(8);
    (void)__hip_atomic_load(&rprog[0], __ATOMIC_ACQUIRE, __HIP_MEMORY_SCOPE_AGENT);
  }
  __syncthreads();

  unsigned xw0[4], xw1[4];
#pragma unroll
  for (int g = 0; g < 4; ++g) xw0[g] = *(const unsigned*)(xbase + xoff[g]);   // t=0
  xbase += 524288;   // -> t=1

  i32x4 zacc = (i32x4){0, 0, 0, 0};
  float cs = 0.f, hh = 0.f;
  __syncthreads();

#define STEP(CUR, XW_CUR, XW_NXT)                                               \
  {                                                                             \
    _Pragma("unroll")                                                           \
    for (int g = 0; g < 4; ++g) XW_NXT[g] = *(const unsigned*)(xbase + xoff[g]);\
    const signed char* hr = hb[CUR ^ 1];                                        \
    i32x4 acc[4][2];                                                            \
    {                                                                           \
      i32x4 a0 = *(const i32x4*)(hr + (c & 1) * 288 + q * 16);                  \
      _Pragma("unroll")                                                         \
      for (int g = 0; g < 4; ++g) {                                             \
        __asm__("v_mfma_i32_16x16x64_i8 %0, %1, %2, %3"                         \
                : "=&v"(acc[g][0]) : "v"(a0), "a"(bw[g][0][0]), "v"(zacc));     \
        __asm__("v_mfma_i32_16x16x64_i8 %0, %1, %2, %3"                         \
                : "=&v"(acc[g][1]) : "v"(a0), "a"(bw[g][1][0]), "v"(zacc));     \
      }                                                                         \
    }                                                                           \
    _Pragma("unroll")                                                           \
    for (int ks = 1; ks < 4; ++ks) {                                            \
      i32x4 a = *(const i32x4*)(hr + (c & 1) * 288 + ks * 64 + q * 16);         \
      _Pragma("unroll")                                                         \
      for (int g = 0; g < 4; ++g) {                                             \
        __asm__("v_mfma_i32_16x16x64_i8 %0, %1, %2, %0"                         \
                : "+v"(acc[g][0]) : "v"(a), "a"(bw[g][0][ks]));                 \
        __asm__("v_mfma_i32_16x16x64_i8 %0, %1, %2, %0"                         \
                : "+v"(acc[g][1]) : "v"(a), "a"(bw[g][1][ks]));                 \
      }                                                                         \
    }                                                                           \
    __asm__ volatile("s_nop 7\n\ts_nop 7\n\ts_nop 7");  /* MFMA->VALU hazard */ \
    float a4[4];                                                                \
    _Pragma("unroll")                                                           \
    for (int g = 0; g < 4; ++g) {                                               \
      int e = tt ? (rsel ? acc[g][1][1] : acc[g][1][0])                         \
                 : (rsel ? acc[g][0][1] : acc[g][0][0]);                        \
      unsigned d = XW_CUR[g];                                                   \
      float xv = rsel ? bfhi(d) : bflo(d);                                      \
      a4[g] = (float)e * sc8[g] + xv;                                           \
    }                                                                           \
    float gi = fsig(a4[0]);                                                     \
    float gf = fsig(a4[1]);                                                     \
    float gg = ftanh(a4[2]);                                                    \
    float go = fsig(a4[3]);                                                     \
    cs = gf * cs + gi * gg;                                                     \
    hh = go * ftanh(cs);                                                        \
    int hq = (int)rintf(hh * 127.f);                                            \
    hb[CUR][rsel * 288 + wid * 32 + tt * 16 + c] = (signed char)hq;             \
    xbase += 524288;                                                            \
    __builtin_amdgcn_s_waitcnt(0xC07F);  /* lgkmcnt(0) only, vmcnt in flight */ \
    __builtin_amdgcn_s_barrier();                                               \
  }

  for (int t = 0; t < TT; t += 2) {
    STEP(0, xw0, xw1)
    if (((t + 2) & 63) == 0 && (t + 2) < TT) {
      // next STEP prefetches t+2 (first step of round (t+2)/64): wait for it
      int j = (t + 2) >> 6;
      if (tid == 0) {
        while (__hip_atomic_load(&rprog[j], __ATOMIC_RELAXED, __HIP_MEMORY_SCOPE_AGENT) < 128)
          __builtin_amdgcn_s_sleep(8);
        (void)__hip_atomic_load(&rprog[j], __ATOMIC_ACQUIRE, __HIP_MEMORY_SCOPE_AGENT);
      }
      __syncthreads();
    }
    STEP(1, xw1, xw0)
  }
#undef STEP

  {
    int n = G * 16 + q8 * 2 + rsel;
    int hu = wid * 32 + tt * 16 + c;
    out[(size_t)n * 256 + hu] = hh;
    out[65536 + (size_t)n * 256 + hu] = cs;
  }
}

// ---------- launch ----------
extern "C" void kernel_launch(void* const* d_in, const int* in_sizes, int n_in,
                              void* d_out, int out_size, void* d_ws, size_t ws_size,
                              hipStream_t stream) {
  const float* x   = (const float*)d_in[0];
  const float* wii = (const float*)d_in[1];
  const float* whi = (const float*)d_in[2];
  const float* wif = (const float*)d_in[3];
  const float* whf = (const float*)d_in[4];
  const float* wig = (const float*)d_in[5];
  const float* whg = (const float*)d_in[6];
  const float* wio = (const float*)d_in[7];
  const float* who = (const float*)d_in[8];
  const float* bii = (const float*)d_in[9];
  const float* bhi = (const float*)d_in[10];
  const float* bif = (const float*)d_in[11];
  const float* bhf = (const float*)d_in[12];
  const float* big_ = (const float*)d_in[13];
  const float* bhg = (const float*)d_in[14];
  const float* bio = (const float*)d_in[15];
  const float* bho = (const float*)d_in[16];

  char* ws = (char*)d_ws;
  int*   rprog  = (int*)(ws);                         // [0..7] rounds, [8] prep
  u16*   Wxb    = (u16*)(ws + 67108864);              //    524,288 B
  signed char* Whq = (signed char*)(ws + 67633152);   //    262,144 B
  float* wscale = (float*)(ws + 67895296);            //      4,096 B
  float* bsum   = (float*)(ws + 67899392);            //      4,096 B
  u16*   xWp    = (u16*)(ws + 67903488);              // 268,435,456 B + pad
  float* out = (float*)d_out;

  hipMemsetAsync(rprog, 0, 64, stream);
  lstm_fused<<<256, 512, 0, stream>>>(x,
                                      wii, whi, wif, whf, wig, whg, wio, who,
                                      bii, bhi, bif, bhf, big_, bhg, bio, bho,
                                      Wxb, Whq, wscale, bsum, xWp, rprog, out);
}